// Round 5
// baseline (254.222 us; speedup 1.0000x reference)
//
#include <hip/hip_runtime.h>
#include <math.h>

// ManifoldAlignmentLoss: B=256, D=512, N=50000, A=8, K=5
// R5: zero contended global atomics.
//   prep -> match (per-block private pair regions, LDS-only atomics)
//        -> dot (slot-space grid-stride, 2-deep pipeline, plain stores)
//        -> topk (block per b, scan + block max-eliminate) -> final (sum).
// R4 lesson: dot was invariant to wave count -> serialized resource = the
// 33K same-address returning atomicAdds. Removed entirely.

constexpr int D = 512;
constexpr int A = 8;
constexpr int K_NEI = 5;
constexpr int CAP = 256;          // per-block pair capacity (mean ~170, sigma ~13 -> 6.5 sigma)
constexpr int DOT_BLOCKS = 2048;  // 8192 waves
constexpr unsigned SENT = 0xFFFFFFFFu;

__device__ __forceinline__ float wave_reduce_add(float v) {
    #pragma unroll
    for (int m = 1; m < 64; m <<= 1) v += __shfl_xor(v, m, 64);
    return v;
}

// ---------------- prep: normalize z rows, pack target attrs ---------------
// grid = B blocks x 64 threads
__global__ __launch_bounds__(64) void prep_kernel(
    const float* __restrict__ z, const int* __restrict__ tattr,
    float* __restrict__ z_norm, unsigned* __restrict__ tpacked)
{
    const int b = blockIdx.x;
    const int lane = threadIdx.x;
    const float4* zrow = (const float4*)(z + (size_t)b * D);
    float4 v0 = zrow[lane * 2 + 0];
    float4 v1 = zrow[lane * 2 + 1];
    float ss = v0.x*v0.x + v0.y*v0.y + v0.z*v0.z + v0.w*v0.w
             + v1.x*v1.x + v1.y*v1.y + v1.z*v1.z + v1.w*v1.w;
    ss = wave_reduce_add(ss);
    const float scale = 1.0f / fmaxf(sqrtf(ss), 1e-12f);
    v0.x *= scale; v0.y *= scale; v0.z *= scale; v0.w *= scale;
    v1.x *= scale; v1.y *= scale; v1.z *= scale; v1.w *= scale;
    float4* orow = (float4*)(z_norm + (size_t)b * D);
    orow[lane * 2 + 0] = v0;
    orow[lane * 2 + 1] = v1;
    if (lane == 0) {
        unsigned p = 0;
        #pragma unroll
        for (int a = 0; a < A; a++)
            p |= ((unsigned)tattr[b * A + a] & 0xFu) << (4 * a);
        tpacked[b] = p;
    }
}

// ------- match: per-block private pair region, LDS atomic only ------------
// grid = ceil(N/256) blocks x 256 threads
__global__ __launch_bounds__(256) void match_kernel(
    const int* __restrict__ trattr, const unsigned* __restrict__ tpacked,
    unsigned* __restrict__ pairs, int* __restrict__ cnt, int N)
{
    __shared__ unsigned s_tp[256];
    __shared__ int s_cnt;

    const int tid = threadIdx.x;
    const int n = blockIdx.x * 256 + tid;
    s_tp[tid] = tpacked[tid];
    if (tid == 0) s_cnt = 0;
    __syncthreads();

    if (n < N) {
        const int4* a4 = (const int4*)(trattr + (size_t)n * A);
        const int4 x = a4[0], y = a4[1];
        const unsigned p =
             ((unsigned)x.x & 0xFu)        | (((unsigned)x.y & 0xFu) << 4)
           | (((unsigned)x.z & 0xFu) << 8)  | (((unsigned)x.w & 0xFu) << 12)
           | (((unsigned)y.x & 0xFu) << 16) | (((unsigned)y.y & 0xFu) << 20)
           | (((unsigned)y.z & 0xFu) << 24) | (((unsigned)y.w & 0xFu) << 28);

        const uint4* tp4 = (const uint4*)s_tp;
        #pragma unroll 4
        for (int bq = 0; bq < 64; bq++) {
            const uint4 t = tp4[bq];
            #pragma unroll
            for (int j = 0; j < 4; j++) {
                const unsigned tv = (j == 0) ? t.x : (j == 1) ? t.y : (j == 2) ? t.z : t.w;
                const unsigned yv = p ^ tv;
                // hi bit of each nibble set iff nibble nonzero
                const unsigned nzhi = ((((yv & 0x77777777u) + 0x77777777u) | yv) & 0x88888888u);
                if (__popc(nzhi) <= 1) {   // >= A-1 matching attrs
                    const int idx = atomicAdd(&s_cnt, 1);   // LDS atomic: cheap
                    if (idx < CAP)
                        pairs[blockIdx.x * CAP + idx] =
                            ((unsigned)n << 8) | (unsigned)(bq * 4 + j);
                }
            }
        }
    }
    __syncthreads();
    if (tid == 0) cnt[blockIdx.x] = min(s_cnt, CAP);
}

// ------- dot: grid-stride over slot space, no atomics, 2-deep pipeline ----
// grid = DOT_BLOCKS x 256 threads; TOT = nblk*CAP slots (CAP==256 -> blk = slot>>8)
__global__ __launch_bounds__(256) void dot_kernel(
    const float* __restrict__ train, const float* __restrict__ z_norm,
    const unsigned* __restrict__ pairs, const int* __restrict__ cnt,
    float* __restrict__ sims, int TOT)
{
    const int lane = threadIdx.x & 63;
    const int w = blockIdx.x * 4 + (threadIdx.x >> 6);
    const int nwaves = DOT_BLOCKS * 4;
    const int niter = (TOT - w + nwaves - 1) / nwaves;   // <= 7
    if (niter <= 0) return;

    // lane t holds iteration t's pair (or SENT for empty/out-of-range slots)
    unsigned mypr = SENT;
    if (lane < niter) {
        const int slot = w + lane * nwaves;               // < TOT by niter def
        if ((slot & (CAP - 1)) < cnt[slot >> 8]) mypr = pairs[slot];
    }

    // prologue: issue loads for iteration 0
    unsigned pr = __shfl(mypr, 0, 64);
    float4 r0 = {0,0,0,0}, r1 = {0,0,0,0}, z0 = {0,0,0,0}, z1 = {0,0,0,0};
    if (pr != SENT) {
        const float4* row4 = (const float4*)(train  + (size_t)(pr >> 8)   * D);
        const float4* zr4  = (const float4*)(z_norm + (size_t)(pr & 255u) * D);
        r0 = row4[lane * 2 + 0]; r1 = row4[lane * 2 + 1];
        z0 = zr4[lane * 2 + 0];  z1 = zr4[lane * 2 + 1];
    }

    for (int t = 0; t < niter; t++) {
        const int slot = w + t * nwaves;
        const bool more = (t + 1 < niter);
        unsigned npr = SENT;
        float4 nr0 = {0,0,0,0}, nr1 = {0,0,0,0}, nz0 = {0,0,0,0}, nz1 = {0,0,0,0};
        if (more) {
            npr = __shfl(mypr, t + 1, 64);
            if (npr != SENT) {
                const float4* nrow4 = (const float4*)(train  + (size_t)(npr >> 8)   * D);
                const float4* nzr4  = (const float4*)(z_norm + (size_t)(npr & 255u) * D);
                nr0 = nrow4[lane * 2 + 0]; nr1 = nrow4[lane * 2 + 1];
                nz0 = nzr4[lane * 2 + 0];  nz1 = nzr4[lane * 2 + 1];
            }
        }

        if (pr != SENT) {
            float ss = r0.x*r0.x + r0.y*r0.y + r0.z*r0.z + r0.w*r0.w
                     + r1.x*r1.x + r1.y*r1.y + r1.z*r1.z + r1.w*r1.w;
            float dd = r0.x*z0.x + r0.y*z0.y + r0.z*z0.z + r0.w*z0.w
                     + r1.x*z1.x + r1.y*z1.y + r1.z*z1.z + r1.w*z1.w;
            #pragma unroll
            for (int m = 1; m < 64; m <<= 1) {
                ss += __shfl_xor(ss, m, 64);
                dd += __shfl_xor(dd, m, 64);
            }
            if (lane == 0) sims[slot] = dd / fmaxf(sqrtf(ss), 1e-12f);
        } else {
            if (lane == 0) sims[slot] = -1e30f;   // sentinel: empty slot
        }

        pr = npr; r0 = nr0; r1 = nr1; z0 = nz0; z1 = nz1;
    }
}

// ------- topk: block per b, scan pair/sim lists, block max-eliminate ------
// grid = B blocks x 256 threads
__global__ __launch_bounds__(256) void topk_kernel(
    const unsigned* __restrict__ pairs, const float* __restrict__ sims,
    float* __restrict__ contrib, int TOT, int Bt)
{
    const int b = blockIdx.x;
    const int tid = threadIdx.x;
    const int lane = tid & 63;
    const int wv = tid >> 6;

    float top[K_NEI];
    #pragma unroll
    for (int k = 0; k < K_NEI; k++) top[k] = -1e30f;
    int mc = 0;

    for (int s = tid; s < TOT; s += 256) {
        const unsigned pr = pairs[s];
        const float v = sims[s];
        // empty slots: sims == -1e30 sentinel (pairs holds poison there)
        if ((pr & 255u) == (unsigned)b && v > -1e29f) {
            mc++;
            if (v > top[K_NEI - 1]) {
                top[K_NEI - 1] = v;
                #pragma unroll
                for (int k = K_NEI - 1; k > 0; k--)
                    if (top[k] > top[k - 1]) { float tt = top[k]; top[k] = top[k - 1]; top[k - 1] = tt; }
            }
        }
    }

    __shared__ int s_mc[4];
    __shared__ float s_wmax[4];

    int mcw = mc;
    #pragma unroll
    for (int m = 1; m < 64; m <<= 1) mcw += __shfl_xor(mcw, m, 64);
    if (lane == 0) s_mc[wv] = mcw;
    __syncthreads();
    const int cntb = s_mc[0] + s_mc[1] + s_mc[2] + s_mc[3];

    float ssum = 0.0f;
    #pragma unroll
    for (int r = 0; r < K_NEI; r++) {
        const float cand = top[0];
        float Mw = cand;
        #pragma unroll
        for (int m = 1; m < 64; m <<= 1) Mw = fmaxf(Mw, __shfl_xor(Mw, m, 64));
        if (lane == 0) s_wmax[wv] = Mw;
        __syncthreads();
        const float M = fmaxf(fmaxf(s_wmax[0], s_wmax[1]), fmaxf(s_wmax[2], s_wmax[3]));
        const int winw = (s_wmax[0] == M) ? 0 : (s_wmax[1] == M) ? 1 : (s_wmax[2] == M) ? 2 : 3;
        if (wv == winw) {
            const unsigned long long bal = __ballot(cand == M);
            const int first = __ffsll(bal) - 1;
            if (lane == first) {
                #pragma unroll
                for (int k = 0; k < K_NEI - 1; k++) top[k] = top[k + 1];
                top[K_NEI - 1] = -1e30f;
            }
        }
        ssum += fmaxf(M, 0.0f);   // N-cnt exact zeros from unmatched entries dominate negatives
        __syncthreads();
    }

    if (tid == 0)
        contrib[b] = (cntb >= K_NEI) ? (1.0f - ssum * (1.0f / K_NEI)) / (float)Bt : 0.0f;
}

// ---------------- final: sum contrib, single wave -------------------------
__global__ __launch_bounds__(64) void final_kernel(
    const float* __restrict__ contrib, float* __restrict__ out, int Bt)
{
    float s = 0.0f;
    for (int i = threadIdx.x; i < Bt; i += 64) s += contrib[i];
    s = wave_reduce_add(s);
    if (threadIdx.x == 0) out[0] = s;
}

extern "C" void kernel_launch(void* const* d_in, const int* in_sizes, int n_in,
                              void* d_out, int out_size, void* d_ws, size_t ws_size,
                              hipStream_t stream)
{
    const float* z      = (const float*)d_in[0];   // [B, D] f32
    const int*   tattr  = (const int*)d_in[1];     // [B, A] i32
    const float* train  = (const float*)d_in[2];   // [N, D] f32
    const int*   trattr = (const int*)d_in[3];     // [N, A] i32
    float* out = (float*)d_out;

    const int B = in_sizes[0] / D;        // 256
    const int N = in_sizes[2] / D;        // 50000
    const int NBLK = (N + 255) / 256;     // 196
    const int TOT = NBLK * CAP;           // 50176 slots

    // ws layout
    char* ws = (char*)d_ws;
    float*    z_norm  = (float*)ws;    ws += (size_t)B * D * sizeof(float);
    unsigned* tpacked = (unsigned*)ws; ws += (size_t)B * sizeof(unsigned);
    int*      cnt     = (int*)ws;      ws += (size_t)NBLK * sizeof(int) + 48;
    unsigned* pairs   = (unsigned*)ws; ws += (size_t)TOT * sizeof(unsigned);
    float*    sims    = (float*)ws;    ws += (size_t)TOT * sizeof(float);
    float*    contrib = (float*)ws;

    prep_kernel<<<B, 64, 0, stream>>>(z, tattr, z_norm, tpacked);
    match_kernel<<<NBLK, 256, 0, stream>>>(trattr, tpacked, pairs, cnt, N);
    dot_kernel<<<DOT_BLOCKS, 256, 0, stream>>>(train, z_norm, pairs, cnt, sims, TOT);
    topk_kernel<<<B, 256, 0, stream>>>(pairs, sims, contrib, TOT, B);
    final_kernel<<<1, 64, 0, stream>>>(contrib, out, B);
}

// Round 6
// 226.452 us; speedup vs baseline: 1.1226x; 1.1226x over previous
//
#include <hip/hip_runtime.h>
#include <math.h>

// ManifoldAlignmentLoss: B=256, D=512, N=50000, A=8, K=5
// R6: deterministic bucket placement (no contended atomics) + quarter-wave dot.
//   prep  -> z_norm, npairs=0
//   match -> compacted pair list (n<<16|rank<<8|b) + per-(blk,b) counts h
//   scan  -> exclusive prefix over blocks per b -> offs, totals cntb
//   dot   -> one pair per 16-lane quarter; writes sims[b*SLOTS+offs+rank]
//   topk  -> wave per b over contiguous bucket -> contrib[b]
//   final -> sum contrib
// R5 lessons: scan-everything topk was 80us (latency-bound); bucketed topk is
// the right shape. Dot's cost theory: DS-pipe (12 shfl/pair) + gather latency.

constexpr int D = 512;
constexpr int A = 8;
constexpr int K_NEI = 5;
constexpr int SLOTS = 512;          // per-b bucket capacity (mean ~130)
constexpr int PAIR_CAP = 65536;     // global pair list cap (mean ~33K)
constexpr int LDS_PAIR_CAP = 512;   // per-block matches (mean ~171, 26 sigma)
constexpr int DOT_BLOCKS = 2048;    // 8192 waves x 4 quarters = 32768 pairs/sweep

__device__ __forceinline__ float wave_reduce_add(float v) {
    #pragma unroll
    for (int m = 1; m < 64; m <<= 1) v += __shfl_xor(v, m, 64);
    return v;
}

// ---------------- prep: normalize z rows, zero npairs ---------------------
// grid = B blocks x 64 threads
__global__ __launch_bounds__(64) void prep_kernel(
    const float* __restrict__ z, float* __restrict__ z_norm,
    int* __restrict__ npairs)
{
    const int b = blockIdx.x;
    const int lane = threadIdx.x;
    const float4* zrow = (const float4*)(z + (size_t)b * D);
    float4 v0 = zrow[lane * 2 + 0];
    float4 v1 = zrow[lane * 2 + 1];
    float ss = v0.x*v0.x + v0.y*v0.y + v0.z*v0.z + v0.w*v0.w
             + v1.x*v1.x + v1.y*v1.y + v1.z*v1.z + v1.w*v1.w;
    ss = wave_reduce_add(ss);
    const float scale = 1.0f / fmaxf(sqrtf(ss), 1e-12f);
    v0.x *= scale; v0.y *= scale; v0.z *= scale; v0.w *= scale;
    v1.x *= scale; v1.y *= scale; v1.z *= scale; v1.w *= scale;
    float4* orow = (float4*)(z_norm + (size_t)b * D);
    orow[lane * 2 + 0] = v0;
    orow[lane * 2 + 1] = v1;
    if (b == 0 && lane == 0) *npairs = 0;
}

// ------- match: compacted pairs with per-(blk,b) rank, counts h -----------
// grid = ceil(N/256) blocks x 256 threads
__global__ __launch_bounds__(256) void match_kernel(
    const int* __restrict__ trattr, const int* __restrict__ tattr,
    unsigned* __restrict__ pairs, int* __restrict__ npairs,
    int* __restrict__ h, int N)
{
    __shared__ unsigned s_tp[256];
    __shared__ unsigned s_pairs[LDS_PAIR_CAP];
    __shared__ int s_hist[256];
    __shared__ int s_cnt, s_base;

    const int tid = threadIdx.x;
    const int n = blockIdx.x * 256 + tid;

    // each thread packs its own target b's attrs (coalesced int4 loads)
    {
        const int4* t4 = (const int4*)(tattr + (size_t)tid * A);
        const int4 x = t4[0], y = t4[1];
        s_tp[tid] = ((unsigned)x.x & 0xFu)        | (((unsigned)x.y & 0xFu) << 4)
                  | (((unsigned)x.z & 0xFu) << 8)  | (((unsigned)x.w & 0xFu) << 12)
                  | (((unsigned)y.x & 0xFu) << 16) | (((unsigned)y.y & 0xFu) << 20)
                  | (((unsigned)y.z & 0xFu) << 24) | (((unsigned)y.w & 0xFu) << 28);
    }
    s_hist[tid] = 0;
    if (tid == 0) s_cnt = 0;
    __syncthreads();

    if (n < N) {
        const int4* a4 = (const int4*)(trattr + (size_t)n * A);
        const int4 x = a4[0], y = a4[1];
        const unsigned p =
             ((unsigned)x.x & 0xFu)        | (((unsigned)x.y & 0xFu) << 4)
           | (((unsigned)x.z & 0xFu) << 8)  | (((unsigned)x.w & 0xFu) << 12)
           | (((unsigned)y.x & 0xFu) << 16) | (((unsigned)y.y & 0xFu) << 20)
           | (((unsigned)y.z & 0xFu) << 24) | (((unsigned)y.w & 0xFu) << 28);

        const uint4* tp4 = (const uint4*)s_tp;
        #pragma unroll 4
        for (int bq = 0; bq < 64; bq++) {
            const uint4 t = tp4[bq];
            #pragma unroll
            for (int j = 0; j < 4; j++) {
                const unsigned tv = (j == 0) ? t.x : (j == 1) ? t.y : (j == 2) ? t.z : t.w;
                const unsigned yv = p ^ tv;
                // hi bit of each nibble set iff nibble nonzero
                const unsigned nzhi = ((((yv & 0x77777777u) + 0x77777777u) | yv) & 0x88888888u);
                if (__popc(nzhi) <= 1) {   // >= A-1 matching attrs
                    const int b = bq * 4 + j;
                    const int rank = atomicAdd(&s_hist[b], 1);   // LDS, distributed
                    const int idx  = atomicAdd(&s_cnt, 1);       // LDS
                    if (idx < LDS_PAIR_CAP && rank < 256)
                        s_pairs[idx] = ((unsigned)n << 16) | ((unsigned)rank << 8)
                                     | (unsigned)b;
                }
            }
        }
    }
    __syncthreads();

    // per-(blk,b) counts, blk-major for coalesced scan
    h[blockIdx.x * 256 + tid] = s_hist[tid];

    const int cnt = min(s_cnt, LDS_PAIR_CAP);
    if (tid == 0) s_base = atomicAdd(npairs, cnt);   // 1 per block, uncontended-ish
    __syncthreads();
    const int base = s_base;
    for (int i = tid; i < cnt; i += 256)
        if (base + i < PAIR_CAP) pairs[base + i] = s_pairs[i];
}

// ------- scan: exclusive prefix over blocks for each b --------------------
// grid = 1 block x 256 threads; thread b scans NBLK entries (coalesced)
__global__ __launch_bounds__(256) void scan_kernel(
    const int* __restrict__ h, int* __restrict__ offs,
    int* __restrict__ cntb, int NBLK)
{
    const int b = threadIdx.x;
    int run = 0;
    for (int blk = 0; blk < NBLK; blk++) {
        const int v = h[blk * 256 + b];
        offs[blk * 256 + b] = run;
        run += v;
    }
    cntb[b] = run;
}

// ------- dot: one pair per 16-lane quarter, deterministic dest ------------
// grid = DOT_BLOCKS x 256 threads
__global__ __launch_bounds__(256) void dot_kernel(
    const float* __restrict__ train, const float* __restrict__ z_norm,
    const unsigned* __restrict__ pairs, const int* __restrict__ npairs,
    const int* __restrict__ offs, float* __restrict__ sims)
{
    const int np = min(*npairs, PAIR_CAP);
    const int tid = threadIdx.x;
    const int lane = tid & 63;
    const int q  = lane >> 4;     // quarter 0..3
    const int ql = lane & 15;     // lane within quarter
    const int w = blockIdx.x * 4 + (tid >> 6);
    const int stride = DOT_BLOCKS * 4 * 4;   // pairs per sweep

    for (int p0 = w * 4; p0 < np; p0 += stride) {
        const int idx = p0 + q;
        const bool active = (idx < np);
        unsigned pr = 0;
        float ss = 0.0f, dd = 0.0f;
        if (active) {
            pr = pairs[idx];
            const int n = (int)(pr >> 16);
            const int b = (int)(pr & 255u);
            const float4* r4 = (const float4*)(train  + (size_t)n * D);
            const float4* z4 = (const float4*)(z_norm + (size_t)b * D);
            #pragma unroll
            for (int j = 0; j < 8; j++) {
                const float4 r  = r4[j * 16 + ql];   // 256B contiguous per quarter
                const float4 zz = z4[j * 16 + ql];
                ss += r.x*r.x  + r.y*r.y  + r.z*r.z  + r.w*r.w;
                dd += r.x*zz.x + r.y*zz.y + r.z*zz.z + r.w*zz.w;
            }
        }
        // reduce within each 16-lane quarter: 4 rounds serve 4 pairs at once
        #pragma unroll
        for (int m = 1; m < 16; m <<= 1) {
            ss += __shfl_xor(ss, m, 64);
            dd += __shfl_xor(dd, m, 64);
        }
        if (active && ql == 0) {
            const int n    = (int)(pr >> 16);
            const int b    = (int)(pr & 255u);
            const int rank = (int)((pr >> 8) & 255u);
            const int blk  = n >> 8;   // pairs from block blk have n in [blk*256, ...)
            const int dest = offs[blk * 256 + b] + rank;
            if (dest < SLOTS)
                sims[(size_t)b * SLOTS + dest] = dd / fmaxf(sqrtf(ss), 1e-12f);
        }
    }
}

// ---------------- topk: one wave per b over contiguous bucket -------------
// grid = B blocks x 64 threads
__global__ __launch_bounds__(64) void topk_kernel(
    const int* __restrict__ cntb, const float* __restrict__ sims,
    float* __restrict__ contrib, int Bt)
{
    const int b = blockIdx.x;
    const int lane = threadIdx.x;
    const int cnt = cntb[b];
    const int m = min(cnt, SLOTS);
    const float* buf = sims + (size_t)b * SLOTS;

    float v[8];
    #pragma unroll
    for (int k = 0; k < 8; k++) {
        const int i = lane + k * 64;
        v[k] = (i < m) ? buf[i] : -1e30f;
    }

    float s = 0.0f;
    #pragma unroll
    for (int r = 0; r < K_NEI; r++) {
        float best = v[0];
        #pragma unroll
        for (int k = 1; k < 8; k++) best = fmaxf(best, v[k]);
        float M = best;
        #pragma unroll
        for (int mm = 1; mm < 64; mm <<= 1) M = fmaxf(M, __shfl_xor(M, mm, 64));
        s += fmaxf(M, 0.0f);   // N-cnt exact zeros from unmatched entries dominate negatives
        const unsigned long long bal = __ballot(best == M);
        const int first = __ffsll(bal) - 1;
        if (lane == first) {
            if      (v[0] == M) v[0] = -1e30f;
            else if (v[1] == M) v[1] = -1e30f;
            else if (v[2] == M) v[2] = -1e30f;
            else if (v[3] == M) v[3] = -1e30f;
            else if (v[4] == M) v[4] = -1e30f;
            else if (v[5] == M) v[5] = -1e30f;
            else if (v[6] == M) v[6] = -1e30f;
            else                v[7] = -1e30f;
        }
    }

    if (lane == 0)
        contrib[b] = (cnt >= K_NEI) ? (1.0f - s * (1.0f / K_NEI)) / (float)Bt : 0.0f;
}

// ---------------- final: sum contrib, single wave -------------------------
__global__ __launch_bounds__(64) void final_kernel(
    const float* __restrict__ contrib, float* __restrict__ out, int Bt)
{
    float s = 0.0f;
    for (int i = threadIdx.x; i < Bt; i += 64) s += contrib[i];
    s = wave_reduce_add(s);
    if (threadIdx.x == 0) out[0] = s;
}

extern "C" void kernel_launch(void* const* d_in, const int* in_sizes, int n_in,
                              void* d_out, int out_size, void* d_ws, size_t ws_size,
                              hipStream_t stream)
{
    const float* z      = (const float*)d_in[0];   // [B, D] f32
    const int*   tattr  = (const int*)d_in[1];     // [B, A] i32
    const float* train  = (const float*)d_in[2];   // [N, D] f32
    const int*   trattr = (const int*)d_in[3];     // [N, A] i32
    float* out = (float*)d_out;

    const int B = in_sizes[0] / D;        // 256
    const int N = in_sizes[2] / D;        // 50000
    const int NBLK = (N + 255) / 256;     // 196

    // ws layout
    char* ws = (char*)d_ws;
    float*    z_norm  = (float*)ws;    ws += (size_t)B * D * sizeof(float);
    int*      h       = (int*)ws;      ws += (size_t)NBLK * 256 * sizeof(int);
    int*      offs    = (int*)ws;      ws += (size_t)NBLK * 256 * sizeof(int);
    int*      cntb    = (int*)ws;      ws += (size_t)B * sizeof(int);
    int*      npairs  = (int*)ws;      ws += 64;
    unsigned* pairs   = (unsigned*)ws; ws += (size_t)PAIR_CAP * sizeof(unsigned);
    float*    sims    = (float*)ws;    ws += (size_t)B * SLOTS * sizeof(float);
    float*    contrib = (float*)ws;

    prep_kernel<<<B, 64, 0, stream>>>(z, z_norm, npairs);
    match_kernel<<<NBLK, 256, 0, stream>>>(trattr, tattr, pairs, npairs, h, N);
    scan_kernel<<<1, 256, 0, stream>>>(h, offs, cntb, NBLK);
    dot_kernel<<<DOT_BLOCKS, 256, 0, stream>>>(train, z_norm, pairs, npairs, offs, sims);
    topk_kernel<<<B, 64, 0, stream>>>(cntb, sims, contrib, B);
    final_kernel<<<1, 64, 0, stream>>>(contrib, out, B);
}

// Round 7
// 195.710 us; speedup vs baseline: 1.2990x; 1.1571x over previous
//
#include <hip/hip_runtime.h>
#include <math.h>

// ManifoldAlignmentLoss: B=256, D=512, N=50000, A=8, K=5
// R7: 3 dispatches, zero scans, zero contended atomics, fixed strided buckets.
//   prep_match: blocks [0,NBLK) match 256 rows -> per-block pair region +
//               per-(blk,b) counts h; blocks [NBLK,NBLK+B) normalize z,
//               sentinel-init sims, zero out.
//   dot:        quarter-wave (16 lanes/pair) over NBLK*256 slot space,
//               writes sims[b*BSTRIDE + blk*CAPB + rank]. No atomics.
//   topk:       wave per b: cnt from h column, per-lane top5 + wave merge,
//               one atomicAdd(out) per b.
// R6 lesson: the serial scan_kernel cost ~50us. R4/R5/R6 lessons: match+dot
// ~44us invariant to waves/atomics/shfl-chain -> suspect dispatch gaps or
// gather structure; this round isolates by minimizing dispatch count.

constexpr int D = 512;
constexpr int A = 8;
constexpr int K_NEI = 5;
constexpr int CAPB = 16;           // per-(blk,b) bucket slots (mean 0.66, P(>=16)~1e-12)
constexpr int CAP_BLK = 256;       // per-block pair region (mean ~171)
constexpr int LDS_PAIR_CAP = 512;
constexpr int DOT_BLOCKS = 2048;   // 8192 waves x 4 quarters

__device__ __forceinline__ float wave_reduce_add(float v) {
    #pragma unroll
    for (int m = 1; m < 64; m <<= 1) v += __shfl_xor(v, m, 64);
    return v;
}

// ---- kernel 1: fused match (blocks < NBLK) + prep/init (blocks >= NBLK) ----
// grid = (NBLK + B) x 256 threads
__global__ __launch_bounds__(256) void prep_match_kernel(
    const float* __restrict__ z, const int* __restrict__ tattr,
    const int* __restrict__ trattr,
    float* __restrict__ z_norm, unsigned* __restrict__ pairs,
    int* __restrict__ cntblk, int* __restrict__ h,
    float* __restrict__ sims, float* __restrict__ out,
    int N, int NBLK, int SIMS_TOT)
{
    const int tid = threadIdx.x;

    if (blockIdx.x >= NBLK) {
        // ---------------- prep part ----------------
        const int b = blockIdx.x - NBLK;
        if (tid < 64) {
            // wave 0: normalize z row b
            const int lane = tid;
            const float4* zrow = (const float4*)(z + (size_t)b * D);
            float4 v0 = zrow[lane * 2 + 0];
            float4 v1 = zrow[lane * 2 + 1];
            float ss = v0.x*v0.x + v0.y*v0.y + v0.z*v0.z + v0.w*v0.w
                     + v1.x*v1.x + v1.y*v1.y + v1.z*v1.z + v1.w*v1.w;
            ss = wave_reduce_add(ss);
            const float scale = 1.0f / fmaxf(sqrtf(ss), 1e-12f);
            v0.x *= scale; v0.y *= scale; v0.z *= scale; v0.w *= scale;
            v1.x *= scale; v1.y *= scale; v1.z *= scale; v1.w *= scale;
            float4* orow = (float4*)(z_norm + (size_t)b * D);
            orow[lane * 2 + 0] = v0;
            orow[lane * 2 + 1] = v1;
        }
        if (b == 0 && tid == 64) out[0] = 0.0f;
        // all 256 threads: sentinel-init a slice of sims (grid-stride float4)
        float4* s4 = (float4*)sims;
        const int n4 = SIMS_TOT >> 2;
        const float4 sent = make_float4(-1e30f, -1e30f, -1e30f, -1e30f);
        for (int i = b * 256 + tid; i < n4; i += 256 * 256) s4[i] = sent;
        return;
    }

    // ---------------- match part ----------------
    __shared__ unsigned s_tp[256];
    __shared__ unsigned s_pairs[LDS_PAIR_CAP];
    __shared__ int s_hist[256];
    __shared__ int s_cnt;

    const int n = blockIdx.x * 256 + tid;

    {   // pack target attrs (coalesced int4 loads, one per thread)
        const int4* t4 = (const int4*)(tattr + (size_t)tid * A);
        const int4 x = t4[0], y = t4[1];
        s_tp[tid] = ((unsigned)x.x & 0xFu)        | (((unsigned)x.y & 0xFu) << 4)
                  | (((unsigned)x.z & 0xFu) << 8)  | (((unsigned)x.w & 0xFu) << 12)
                  | (((unsigned)y.x & 0xFu) << 16) | (((unsigned)y.y & 0xFu) << 20)
                  | (((unsigned)y.z & 0xFu) << 24) | (((unsigned)y.w & 0xFu) << 28);
    }
    s_hist[tid] = 0;
    if (tid == 0) s_cnt = 0;
    __syncthreads();

    if (n < N) {
        const int4* a4 = (const int4*)(trattr + (size_t)n * A);
        const int4 x = a4[0], y = a4[1];
        const unsigned p =
             ((unsigned)x.x & 0xFu)        | (((unsigned)x.y & 0xFu) << 4)
           | (((unsigned)x.z & 0xFu) << 8)  | (((unsigned)x.w & 0xFu) << 12)
           | (((unsigned)y.x & 0xFu) << 16) | (((unsigned)y.y & 0xFu) << 20)
           | (((unsigned)y.z & 0xFu) << 24) | (((unsigned)y.w & 0xFu) << 28);

        const uint4* tp4 = (const uint4*)s_tp;
        #pragma unroll 4
        for (int bq = 0; bq < 64; bq++) {
            const uint4 t = tp4[bq];
            #pragma unroll
            for (int j = 0; j < 4; j++) {
                const unsigned tv = (j == 0) ? t.x : (j == 1) ? t.y : (j == 2) ? t.z : t.w;
                const unsigned yv = p ^ tv;
                // hi bit of each nibble set iff nibble nonzero
                const unsigned nzhi = ((((yv & 0x77777777u) + 0x77777777u) | yv) & 0x88888888u);
                if (__popc(nzhi) <= 1) {   // >= A-1 matching attrs
                    const int b = bq * 4 + j;
                    const int rank = atomicAdd(&s_hist[b], 1);   // LDS, distributed
                    if (rank < CAPB) {
                        const int idx = atomicAdd(&s_cnt, 1);    // LDS
                        if (idx < LDS_PAIR_CAP)
                            s_pairs[idx] = ((unsigned)n << 16)
                                         | ((unsigned)rank << 8) | (unsigned)b;
                    }
                }
            }
        }
    }
    __syncthreads();

    h[blockIdx.x * 256 + tid] = s_hist[tid];   // true counts (validity + topk cnt)
    const int cnt = min(s_cnt, min(LDS_PAIR_CAP, CAP_BLK));
    if (tid == 0) cntblk[blockIdx.x] = cnt;
    for (int i = tid; i < cnt; i += 256)
        pairs[blockIdx.x * CAP_BLK + i] = s_pairs[i];
}

// ---- kernel 2: dot, one pair per 16-lane quarter, deterministic dest ----
// grid = DOT_BLOCKS x 256; slot space = NBLK*CAP_BLK
__global__ __launch_bounds__(256) void dot_kernel(
    const float* __restrict__ train, const float* __restrict__ z_norm,
    const unsigned* __restrict__ pairs, const int* __restrict__ cntblk,
    float* __restrict__ sims, int TOT, int BSTRIDE)
{
    const int tid = threadIdx.x;
    const int lane = tid & 63;
    const int q  = lane >> 4;     // quarter 0..3
    const int ql = lane & 15;     // lane within quarter
    const int Q = (blockIdx.x * 4 + (tid >> 6)) * 4 + q;   // global quarter id
    const int QTOT = DOT_BLOCKS * 16;

    for (int slot = Q; slot < TOT; slot += QTOT) {
        const int blk = slot >> 8;
        const int idx = slot & (CAP_BLK - 1);
        const bool active = (idx < cntblk[blk]);
        unsigned pr = 0;
        float ss = 0.0f, dd = 0.0f;
        if (active) {
            pr = pairs[slot];
            const int n = (int)(pr >> 16);
            const int b = (int)(pr & 255u);
            const float4* r4 = (const float4*)(train  + (size_t)n * D);
            const float4* z4 = (const float4*)(z_norm + (size_t)b * D);
            #pragma unroll
            for (int j = 0; j < 8; j++) {
                const float4 r  = r4[j * 16 + ql];   // 256B contiguous per quarter
                const float4 zz = z4[j * 16 + ql];
                ss += r.x*r.x  + r.y*r.y  + r.z*r.z  + r.w*r.w;
                dd += r.x*zz.x + r.y*zz.y + r.z*zz.z + r.w*zz.w;
            }
        }
        // reduce within each 16-lane quarter (4 rounds serve 4 pairs at once)
        #pragma unroll
        for (int m = 1; m < 16; m <<= 1) {
            ss += __shfl_xor(ss, m, 64);
            dd += __shfl_xor(dd, m, 64);
        }
        if (active && ql == 0) {
            const int b    = (int)(pr & 255u);
            const int rank = (int)((pr >> 8) & 255u);
            sims[(size_t)b * BSTRIDE + blk * CAPB + rank] =
                dd / fmaxf(sqrtf(ss), 1e-12f);
        }
    }
}

// ---- kernel 3: topk, one wave per b over strided bucket -------------------
// grid = B x 64
__global__ __launch_bounds__(64) void topk_kernel(
    const int* __restrict__ h, const float* __restrict__ sims,
    float* __restrict__ out, int NBLK, int BSTRIDE, int Bt)
{
    const int b = blockIdx.x;
    const int lane = threadIdx.x;

    // true match count for this b: sum h column (stride-256 ints)
    int c = 0;
    for (int blk = lane; blk < NBLK; blk += 64) c += h[blk * 256 + b];
    c = (int)wave_reduce_add((float)c);   // small ints, exact in fp32

    // per-lane top-5 insertion over the bucket (sentinel -1e30 never inserts)
    float top[K_NEI];
    #pragma unroll
    for (int k = 0; k < K_NEI; k++) top[k] = -1e30f;
    const float* buf = sims + (size_t)b * BSTRIDE;
    for (int i = lane; i < BSTRIDE; i += 64) {
        const float v = buf[i];
        if (v > top[K_NEI - 1]) {
            top[K_NEI - 1] = v;
            #pragma unroll
            for (int k = K_NEI - 1; k > 0; k--)
                if (top[k] > top[k - 1]) { float t = top[k]; top[k] = top[k - 1]; top[k - 1] = t; }
        }
    }

    // 5-round wave max-eliminate over per-lane sorted lists
    float s = 0.0f;
    #pragma unroll
    for (int r = 0; r < K_NEI; r++) {
        float M = top[0];
        #pragma unroll
        for (int m = 1; m < 64; m <<= 1) M = fmaxf(M, __shfl_xor(M, m, 64));
        s += fmaxf(M, 0.0f);   // zeros from unmatched entries dominate negatives
        const unsigned long long bal = __ballot(top[0] == M);
        const int first = __ffsll(bal) - 1;
        if (lane == first) {
            #pragma unroll
            for (int k = 0; k < K_NEI - 1; k++) top[k] = top[k + 1];
            top[K_NEI - 1] = -1e30f;
        }
    }

    if (lane == 0) {
        const float contrib = (c >= K_NEI) ? (1.0f - s * (1.0f / K_NEI)) : 0.0f;
        atomicAdd(out, contrib / (float)Bt);
    }
}

extern "C" void kernel_launch(void* const* d_in, const int* in_sizes, int n_in,
                              void* d_out, int out_size, void* d_ws, size_t ws_size,
                              hipStream_t stream)
{
    const float* z      = (const float*)d_in[0];   // [B, D] f32
    const int*   tattr  = (const int*)d_in[1];     // [B, A] i32
    const float* train  = (const float*)d_in[2];   // [N, D] f32
    const int*   trattr = (const int*)d_in[3];     // [N, A] i32
    float* out = (float*)d_out;

    const int B = in_sizes[0] / D;        // 256
    const int N = in_sizes[2] / D;        // 50000
    const int NBLK = (N + 255) / 256;     // 196
    const int TOT = NBLK * CAP_BLK;       // 50176 slots
    const int BSTRIDE = NBLK * CAPB;      // 3136 bucket entries per b
    const int SIMS_TOT = B * BSTRIDE;     // 802816 floats

    // ws layout
    char* ws = (char*)d_ws;
    float*    z_norm  = (float*)ws;    ws += (size_t)B * D * sizeof(float);
    int*      h       = (int*)ws;      ws += (size_t)NBLK * 256 * sizeof(int);
    int*      cntblk  = (int*)ws;      ws += ((size_t)NBLK * sizeof(int) + 63) & ~63ull;
    unsigned* pairs   = (unsigned*)ws; ws += (size_t)TOT * sizeof(unsigned);
    float*    sims    = (float*)ws;

    prep_match_kernel<<<NBLK + B, 256, 0, stream>>>(
        z, tattr, trattr, z_norm, pairs, cntblk, h, sims, out, N, NBLK, SIMS_TOT);
    dot_kernel<<<DOT_BLOCKS, 256, 0, stream>>>(
        train, z_norm, pairs, cntblk, sims, TOT, BSTRIDE);
    topk_kernel<<<B, 64, 0, stream>>>(h, sims, out, NBLK, BSTRIDE, B);
}